// Round 6
// baseline (277.018 us; speedup 1.0000x reference)
//
#include <hip/hip_runtime.h>

#define CROP_H 14
#define CROP_W 14
#define IMG_H 200
#define IMG_W 200
#define IMG_C 256
#define N_IMG 8
#define N_BOXES 1000
#define PLANE (IMG_H * IMG_W)
#define ELEMS_PER_BOX (IMG_C * CROP_H * CROP_W)   // 50176
#define BLOCKS_PER_BOX (ELEMS_PER_BOX / 256)      // 196

// Kernel A: stable-bin the 1000 boxes by image index n (8 bins) AND
// precompute per-(box,t) sample coordinates in_y/in_x (masked -> -1).
__global__ __launch_bounds__(512) void prep_kernel(
    const float* __restrict__ boxes, const int* __restrict__ box_idx,
    int* __restrict__ order, float* __restrict__ ytab, float* __restrict__ xtab)
{
    __shared__ int counts[N_IMG];
    __shared__ int offsets[N_IMG];
    int tid  = threadIdx.x;
    int wave = tid >> 6;
    int lane = tid & 63;

    int cnt = 0;
    for (int i = lane; i < N_BOXES; i += 64) cnt += (box_idx[i] == wave) ? 1 : 0;
    for (int off = 32; off; off >>= 1) cnt += __shfl_down(cnt, off);
    if (lane == 0) counts[wave] = cnt;
    __syncthreads();
    if (tid == 0) {
        int s = 0;
        for (int i = 0; i < N_IMG; i++) { offsets[i] = s; s += counts[i]; }
    }
    __syncthreads();

    int base = offsets[wave];
    for (int i0 = 0; i0 < N_BOXES; i0 += 64) {
        int i = i0 + lane;
        bool p = (i < N_BOXES) && (box_idx[i] == wave);
        unsigned long long m = __ballot(p);
        unsigned long long below = m & ((1ull << lane) - 1ull);
        if (p) order[base + __popcll(below)] = i;
        base += __popcll(m);
    }

    // Coordinate tables. Reference arithmetic order exactly (IEEE divide).
    for (int i = tid; i < N_BOXES * CROP_H; i += 512) {
        int b = i / CROP_H;
        int t = i % CROP_H;
        float y1 = boxes[b * 4 + 0];
        float x1 = boxes[b * 4 + 1];
        float y2 = boxes[b * 4 + 2];
        float x2 = boxes[b * 4 + 3];
        float h_scale = (y2 - y1) * (float)(IMG_H - 1) / (float)(CROP_H - 1);
        float w_scale = (x2 - x1) * (float)(IMG_W - 1) / (float)(CROP_W - 1);
        float vy = y1 * (float)(IMG_H - 1) + (float)t * h_scale;
        float vx = x1 * (float)(IMG_W - 1) + (float)t * w_scale;
        ytab[i] = ((vy > (float)(IMG_H - 1)) || (vy < 0.0f)) ? -1.0f : vy;
        xtab[i] = ((vx > (float)(IMG_W - 1)) || (vx < 0.0f)) ? -1.0f : vx;
    }
}

// Kernel B: direct bilinear, channel-major/box-minor n-grouped schedule.
// Horizontal tap pairs merged into one unaligned dwordx2 per row ->
// half the L1 line-lookups of 4 scalar taps.
__global__ __launch_bounds__(256) void crop_resize_kernel(
    const float* __restrict__ image,   // (8,256,200,200)
    const int*   __restrict__ box_idx, // (1000,)
    const int*   __restrict__ order,   // (1000,) n-grouped box ids
    const float* __restrict__ ytab,    // (1000,14) in_y or -1
    const float* __restrict__ xtab,    // (1000,14) in_x or -1
    float*       __restrict__ out)     // (1000,256,14,14)
{
    int pos    = blockIdx.x % N_BOXES;          // box position (n-grouped)
    int within = blockIdx.x / N_BOXES;          // channel-chunk [0,196)
    int b      = order[pos];                    // uniform per block
    int elem   = within * 256 + threadIdx.x;    // [0, 50176)

    int x = elem % CROP_W;
    int t = elem / CROP_W;
    int y = t % CROP_H;
    int c = t / CROP_H;

    float vy = ytab[b * CROP_H + y];
    float vx = xtab[b * CROP_H + x];

    size_t oidx = (size_t)b * ELEMS_PER_BOX + elem;

    if ((vy < 0.0f) || (vx < 0.0f)) {
        __builtin_nontemporal_store(0.0f, &out[oidx]);
        return;
    }

    int ty = (int)floorf(vy);
    int by = (int)ceilf(vy);
    int lx = (int)floorf(vx);
    int rx = (int)ceilf(vx);
    float yl = vy - (float)ty;
    float xl = vx - (float)lx;

    int n = box_idx[b];
    const float* __restrict__ plane =
        image + ((size_t)n * IMG_C + c) * (size_t)PLANE;

    int basex = min(lx, IMG_W - 2);   // keep the 2-float window in-bounds
    const float* pt = plane + ty * IMG_W + basex;
    const float* pb = plane + by * IMG_W + basex;

    float2 vt, vbo;
    __builtin_memcpy(&vt,  pt, sizeof(float2));   // unaligned dwordx2
    __builtin_memcpy(&vbo, pb, sizeof(float2));

    // lx > basex only when lx == 199 (then rx == lx and xl == 0).
    float tl = (lx > basex) ? vt.y  : vt.x;
    float tr = vt.y;    // used only when rx > lx (else xl==0 kills it)...
    float bl = (lx > basex) ? vbo.y : vbo.x;
    float br = vbo.y;
    // When rx == lx, force tr/br to tl/bl so 0*garbage can't make NaN.
    if (rx == lx) { tr = tl; br = bl; }

    float top = tl + xl * (tr - tl);
    float bot = bl + xl * (br - bl);
    float v   = top + yl * (bot - top);
    __builtin_nontemporal_store(v, &out[oidx]);
}

extern "C" void kernel_launch(void* const* d_in, const int* in_sizes, int n_in,
                              void* d_out, int out_size, void* d_ws, size_t ws_size,
                              hipStream_t stream) {
    const float* image   = (const float*)d_in[0];
    const float* boxes   = (const float*)d_in[1];
    const int*   box_idx = (const int*)d_in[2];
    float* out  = (float*)d_out;

    // d_ws layout: order (1000 int) | ytab (1000*14 f32) | xtab (1000*14 f32)
    int*   order = (int*)d_ws;
    float* ytab  = (float*)((char*)d_ws + 4096);
    float* xtab  = ytab + N_BOXES * CROP_H;

    prep_kernel<<<1, 512, 0, stream>>>(boxes, box_idx, order, ytab, xtab);

    int grid = N_BOXES * BLOCKS_PER_BOX;  // 196,000 blocks
    crop_resize_kernel<<<grid, 256, 0, stream>>>(image, box_idx, order, ytab, xtab, out);
}